// Round 1
// baseline (402.538 us; speedup 1.0000x reference)
//
#include <hip/hip_runtime.h>
#include <stdint.h>
#include <math.h>

typedef unsigned short u16;
typedef __attribute__((ext_vector_type(4))) float f32x4;
typedef __attribute__((ext_vector_type(8))) __bf16 bf16x8;

#define DEV static __device__ __forceinline__

typedef __attribute__((address_space(1))) void gvoid;
typedef __attribute__((address_space(3))) void lvoid;

DEV float bf2f(u16 u){ uint32_t v = ((uint32_t)u) << 16; float f; __builtin_memcpy(&f, &v, 4); return f; }
DEV u16 f2bf(float f){ uint32_t v; __builtin_memcpy(&v, &f, 4); v = (v + 0x7fffu + ((v >> 16) & 1u)) >> 16; return (u16)v; }

DEV void cp16(const void* g, void* l){
  __builtin_amdgcn_global_load_lds((gvoid*)g, (lvoid*)l, 16, 0, 0);
}
DEV f32x4 mfma16(bf16x8 a, bf16x8 b, f32x4 c){
  return __builtin_amdgcn_mfma_f32_16x16x32_bf16(a, b, c, 0, 0, 0);
}

// ---------------------------------------------------------------------------
// AdaLN: mods[b][6144] = silu(c[b]) @ adaln_w + adaln_b   (two-stage for ILP)
// ---------------------------------------------------------------------------
__global__ void __launch_bounds__(256) adaln1(const float* __restrict__ c,
                                              const float* __restrict__ w,
                                              float* __restrict__ part)
{
  __shared__ float sc[256]; // [2][128] silu(c) slice
  int k0 = blockIdx.y * 128;
  {
    int i = threadIdx.x;           // 256 threads cover 2*128
    int b = i >> 7, kk = i & 127;
    float v = c[b * 1024 + k0 + kk];
    sc[i] = v / (1.f + __expf(-v));
  }
  __syncthreads();
  int col = blockIdx.x * 256 + threadIdx.x;
  float a0 = 0.f, a1 = 0.f;
  #pragma unroll 8
  for (int k = 0; k < 128; ++k){
    float wv = w[(size_t)(k0 + k) * 6144 + col];
    a0 += sc[k] * wv;
    a1 += sc[128 + k] * wv;
  }
  part[((size_t)blockIdx.y * 2 + 0) * 6144 + col] = a0;
  part[((size_t)blockIdx.y * 2 + 1) * 6144 + col] = a1;
}

__global__ void __launch_bounds__(256) adaln2(const float* __restrict__ part,
                                              const float* __restrict__ bias,
                                              float* __restrict__ mods)
{
  int i = blockIdx.x * 256 + threadIdx.x;   // 2*6144
  int b = i / 6144, col = i % 6144;
  float a = bias[col];
  #pragma unroll
  for (int r = 0; r < 8; ++r) a += part[((size_t)r * 2 + b) * 6144 + col];
  mods[i] = a;
}

// ---------------------------------------------------------------------------
// RoPE table: ctab/stab[t*32+i] = cos/sin(pos[t] * 10000^(-i/32))
// ---------------------------------------------------------------------------
__global__ void __launch_bounds__(256) rope_table(const int* __restrict__ pos,
                                                  float* __restrict__ ct,
                                                  float* __restrict__ st)
{
  int idx = blockIdx.x * 256 + threadIdx.x;   // T*32 = 65536
  int t = idx >> 5, i = idx & 31;
  float freq = expf(-0.28782313662425575f * (float)i);  // ln(10000)/32
  float ang = (float)pos[t] * freq;
  ct[idx] = cosf(ang);
  st[idx] = sinf(ang);
}

// ---------------------------------------------------------------------------
// RMSNorm (no affine) + AdaLN modulate -> bf16.  One block per (b,t) row.
// ---------------------------------------------------------------------------
__global__ void __launch_bounds__(256) rmsmod(const float* __restrict__ x,
                                              const float* __restrict__ mods,
                                              u16* __restrict__ out,
                                              int shift_off, int scale_off)
{
  __shared__ float wsum[4];
  int row = blockIdx.x;            // b*2048 + t
  int b = row >> 11;
  const float4 v = ((const float4*)(x + (size_t)row * 1024))[threadIdx.x];
  float ss = v.x * v.x + v.y * v.y + v.z * v.z + v.w * v.w;
  #pragma unroll
  for (int m = 1; m < 64; m <<= 1) ss += __shfl_xor(ss, m);
  if ((threadIdx.x & 63) == 0) wsum[threadIdx.x >> 6] = ss;
  __syncthreads();
  float tot = wsum[0] + wsum[1] + wsum[2] + wsum[3];
  float rr = rsqrtf(tot * (1.f / 1024.f) + 1e-6f);
  const float* mb = mods + (size_t)b * 6144;
  int d0 = threadIdx.x * 4;
  ushort4 o;
  o.x = f2bf(v.x * rr * (1.f + mb[scale_off + d0 + 0]) + mb[shift_off + d0 + 0]);
  o.y = f2bf(v.y * rr * (1.f + mb[scale_off + d0 + 1]) + mb[shift_off + d0 + 1]);
  o.z = f2bf(v.z * rr * (1.f + mb[scale_off + d0 + 2]) + mb[shift_off + d0 + 2]);
  o.w = f2bf(v.w * rr * (1.f + mb[scale_off + d0 + 3]) + mb[shift_off + d0 + 3]);
  ((ushort4*)(out + (size_t)row * 1024))[threadIdx.x] = o;
}

// ---------------------------------------------------------------------------
// Weight transpose + cast: in f32 [R][C] -> out bf16 [C][R]
// ---------------------------------------------------------------------------
__global__ void __launch_bounds__(256) transpose_w(const float* __restrict__ in,
                                                   u16* __restrict__ out, int R, int C)
{
  __shared__ float t[32][33];
  int tx = threadIdx.x & 31, ty = threadIdx.x >> 5;
  int c0 = blockIdx.x * 32, r0 = blockIdx.y * 32;
  #pragma unroll
  for (int i = 0; i < 4; ++i) t[ty + 8 * i][tx] = in[(size_t)(r0 + ty + 8 * i) * C + c0 + tx];
  __syncthreads();
  #pragma unroll
  for (int i = 0; i < 4; ++i) out[(size_t)(c0 + ty + 8 * i) * R + r0 + tx] = f2bf(t[tx][ty + 8 * i]);
}

// ---------------------------------------------------------------------------
// GEMM: C[M,N] = A[M,K](bf16,row) * Bt[N,K](bf16,row)^T, fused epilogues.
// 128x128 tile, BK=32, 4 waves, global_load_lds(16B) staging, 16x16x32 MFMA.
// EPI: 0 = bf16 store; 1 = x + gate*(C+bias) f32; 2 = silu(C) bf16;
//      3 = aux*C bf16; 4 = res + gate*C f32
// ---------------------------------------------------------------------------
template<int EPI>
__global__ void __launch_bounds__(256) gemm_bt(const u16* __restrict__ A,
                                               const u16* __restrict__ Bt,
                                               int M, int N, int K,
                                               const float* __restrict__ mods, int gate_off,
                                               const float* __restrict__ bias,
                                               const float* __restrict__ res,
                                               const u16* __restrict__ aux,
                                               float* __restrict__ outf,
                                               u16* __restrict__ outb)
{
  __shared__ __align__(16) u16 Ash[128 * 32];
  __shared__ __align__(16) u16 Bsh[128 * 32];
  const int tid = threadIdx.x;
  const int l = tid & 63, w = tid >> 6;
  const int m0 = blockIdx.y * 128, n0 = blockIdx.x * 128;
  const int wr = (w >> 1) * 64, wc = (w & 1) * 64;
  const int fr = l & 15, fg = l >> 4;
  f32x4 acc[4][4] = {};

  for (int kt = 0; kt < K; kt += 32) {
    __syncthreads();   // prior-iter LDS reads done
    #pragma unroll
    for (int p = 0; p < 2; ++p) {
      int slot = p * 256 + tid;
      int r = slot >> 2, kp = slot & 3;
      cp16(A + (size_t)(m0 + r) * K + kt + kp * 8, Ash + slot * 8);
      cp16(Bt + (size_t)(n0 + r) * K + kt + kp * 8, Bsh + slot * 8);
    }
    __syncthreads();   // staging visible (vmcnt drained at barrier)
    bf16x8 af[4], bfr[4];
    #pragma unroll
    for (int m = 0; m < 4; ++m) af[m] = *(const bf16x8*)(Ash + (wr + m * 16 + fr) * 32 + fg * 8);
    #pragma unroll
    for (int n = 0; n < 4; ++n) bfr[n] = *(const bf16x8*)(Bsh + (wc + n * 16 + fr) * 32 + fg * 8);
    #pragma unroll
    for (int m = 0; m < 4; ++m)
      #pragma unroll
      for (int n = 0; n < 4; ++n)
        acc[m][n] = mfma16(af[m], bfr[n], acc[m][n]);
  }

  #pragma unroll
  for (int m = 0; m < 4; ++m)
  #pragma unroll
  for (int n = 0; n < 4; ++n)
  #pragma unroll
  for (int j = 0; j < 4; ++j) {
    int row = m0 + wr + m * 16 + fg * 4 + j;
    int col = n0 + wc + n * 16 + fr;
    size_t idx = (size_t)row * N + col;
    float v = acc[m][n][j];
    if (EPI == 0) {
      outb[idx] = f2bf(v);
    } else if (EPI == 1) {
      int b = row >> 11;
      outf[idx] = res[idx] + mods[(size_t)b * 6144 + gate_off + col] * (v + bias[col]);
    } else if (EPI == 2) {
      outb[idx] = f2bf(v / (1.f + __expf(-v)));
    } else if (EPI == 3) {
      outb[idx] = f2bf(bf2f(aux[idx]) * v);
    } else {
      int b = row >> 11;
      outf[idx] = res[idx] + mods[(size_t)b * 6144 + gate_off + col] * v;
    }
  }
}

// ---------------------------------------------------------------------------
// qk-norm (per-head RMS, affine) + RoPE; also repack v.
// qkv bf16 [B,T,3D] -> q/k/v bf16 [B,H,T,Dh]; q pre-scaled by 1/sqrt(Dh).
// One wave per (b,t,h); lane = d.
// ---------------------------------------------------------------------------
__global__ void __launch_bounds__(256) qknorm_rope(const u16* __restrict__ qkv,
                                                   const float* __restrict__ lnq,
                                                   const float* __restrict__ lnk,
                                                   const float* __restrict__ ctab,
                                                   const float* __restrict__ stab,
                                                   u16* __restrict__ qo,
                                                   u16* __restrict__ ko,
                                                   u16* __restrict__ vo)
{
  int r = blockIdx.x * 4 + (threadIdx.x >> 6);   // (b*2048 + t)*16 + h
  int l = threadIdx.x & 63;
  int h = r & 15, t = (r >> 4) & 2047, b = r >> 15;
  const u16* base = qkv + ((size_t)(b * 2048 + t)) * 3072 + h * 64 + l;
  float q = bf2f(base[0]);
  float k = bf2f(base[1024]);
  float sq = q * q, sk = k * k;
  #pragma unroll
  for (int m = 1; m < 64; m <<= 1) { sq += __shfl_xor(sq, m); sk += __shfl_xor(sk, m); }
  float rq = rsqrtf(sq * (1.f / 64.f) + 1e-6f);
  float rk = rsqrtf(sk * (1.f / 64.f) + 1e-6f);
  float yq = q * rq * lnq[l];
  float yk = k * rk * lnk[l];
  float cs = ctab[t * 32 + (l & 31)];
  float sn = stab[t * 32 + (l & 31)];
  float pq = __shfl_xor(yq, 32);
  float pk = __shfl_xor(yk, 32);
  float rotq = (l < 32) ? -pq : pq;
  float rotk = (l < 32) ? -pk : pk;
  float oq = (yq * cs + rotq * sn) * 0.125f;   // fold 1/sqrt(64)
  float ok = yk * cs + rotk * sn;
  size_t oidx = ((size_t)(b * 16 + h) * 2048 + t) * 64 + l;
  qo[oidx] = f2bf(oq);
  ko[oidx] = f2bf(ok);
  vo[oidx] = base[2048];
}

// ---------------------------------------------------------------------------
// Flash attention: q/k/v bf16 [B,H,T,64] -> out bf16 [B,T,D] (head-interleaved)
// block = 4 waves, 64 q-rows per block (16/wave); 64-key tiles in LDS.
// K and V^T tiles XOR-swizzled (^((row&7)<<4)) to kill 16-way conflicts.
// ---------------------------------------------------------------------------
__global__ void __launch_bounds__(256) flash_attn(const u16* __restrict__ qg,
                                                  const u16* __restrict__ kg,
                                                  const u16* __restrict__ vg,
                                                  u16* __restrict__ og)
{
  __shared__ __align__(16) u16 Ksh[64 * 64];
  __shared__ __align__(16) u16 Vsh[64 * 64];   // transposed: [d][k]
  __shared__ __align__(16) u16 Psh[4 * 16 * 64];
  char* Kb = (char*)Ksh; char* Vb = (char*)Vsh; char* Pb = (char*)Psh;
  const int tid = threadIdx.x, l = tid & 63, w = tid >> 6;
  const int fr = l & 15, fg = l >> 4;
  const int qt = blockIdx.x, h = blockIdx.y, b = blockIdx.z;
  const int bh = b * 16 + h;

  bf16x8 qf[2];
  {
    const u16* qp = qg + ((size_t)bh * 2048 + qt * 64 + w * 16 + fr) * 64 + fg * 8;
    qf[0] = *(const bf16x8*)(qp);
    qf[1] = *(const bf16x8*)(qp + 32);
  }
  f32x4 oacc[4] = {};
  float mrun[4], lrun[4];
  #pragma unroll
  for (int j = 0; j < 4; ++j) { mrun[j] = -__builtin_inff(); lrun[j] = 0.f; }

  for (int kv0 = 0; kv0 < 2048; kv0 += 64) {
    __syncthreads();   // prior-iter LDS reads done
    #pragma unroll
    for (int p = 0; p < 2; ++p) {   // stage K [64][64], swizzled
      int slot = p * 256 + tid;
      int kr = slot >> 3, cp = slot & 7;
      uint4 val = *(const uint4*)(kg + ((size_t)bh * 2048 + kv0 + kr) * 64 + cp * 8);
      *(uint4*)(Kb + kr * 128 + ((cp ^ (kr & 7)) << 4)) = val;
    }
    {                               // stage V^T [d][k], swizzled
      int kr = l;
      #pragma unroll
      for (int p = 0; p < 2; ++p) {
        int d0 = (w + p * 4) * 8;
        uint4 val = *(const uint4*)(vg + ((size_t)bh * 2048 + kv0 + kr) * 64 + d0);
        const u16* pu = (const u16*)&val;
        #pragma unroll
        for (int jj = 0; jj < 8; ++jj)
          *(u16*)(Vb + (d0 + jj) * 128 + ((kr * 2) ^ (jj << 4))) = pu[jj];
      }
    }
    __syncthreads();

    // S = Q K^T (q pre-scaled)
    f32x4 sacc[4];
    #pragma unroll
    for (int n = 0; n < 4; ++n) {
      f32x4 z = {0.f, 0.f, 0.f, 0.f};
      #pragma unroll
      for (int kk = 0; kk < 2; ++kk) {
        int krow = n * 16 + fr;
        int dby = (kk * 32 + fg * 8) * 2;
        bf16x8 kf = *(const bf16x8*)(Kb + krow * 128 + (dby ^ ((krow & 7) << 4)));
        z = mfma16(qf[kk], kf, z);
      }
      sacc[n] = z;
    }

    // online softmax over 64 keys (rows live in 16-lane groups)
    float mx[4];
    #pragma unroll
    for (int j = 0; j < 4; ++j)
      mx[j] = fmaxf(fmaxf(sacc[0][j], sacc[1][j]), fmaxf(sacc[2][j], sacc[3][j]));
    #pragma unroll
    for (int mask = 1; mask < 16; mask <<= 1)
      #pragma unroll
      for (int j = 0; j < 4; ++j) mx[j] = fmaxf(mx[j], __shfl_xor(mx[j], mask));
    float scl[4];
    #pragma unroll
    for (int j = 0; j < 4; ++j) {
      float mn = fmaxf(mrun[j], mx[j]);
      scl[j] = __expf(mrun[j] - mn);
      mrun[j] = mn;
    }
    float pv[4][4], sm[4];
    #pragma unroll
    for (int n = 0; n < 4; ++n)
      #pragma unroll
      for (int j = 0; j < 4; ++j) pv[n][j] = __expf(sacc[n][j] - mrun[j]);
    #pragma unroll
    for (int j = 0; j < 4; ++j) sm[j] = pv[0][j] + pv[1][j] + pv[2][j] + pv[3][j];
    #pragma unroll
    for (int mask = 1; mask < 16; mask <<= 1)
      #pragma unroll
      for (int j = 0; j < 4; ++j) sm[j] += __shfl_xor(sm[j], mask);
    #pragma unroll
    for (int j = 0; j < 4; ++j) lrun[j] = lrun[j] * scl[j] + sm[j];
    #pragma unroll
    for (int dt = 0; dt < 4; ++dt)
      #pragma unroll
      for (int j = 0; j < 4; ++j) oacc[dt][j] *= scl[j];

    // P -> LDS (bf16, swizzled), per-wave region
    #pragma unroll
    for (int n = 0; n < 4; ++n)
      #pragma unroll
      for (int j = 0; j < 4; ++j) {
        int rl = fg * 4 + j;
        int cby = (n * 16 + fr) * 2;
        *(u16*)(Pb + w * 2048 + rl * 128 + (cby ^ ((rl & 7) << 4))) = f2bf(pv[n][j]);
      }
    __syncthreads();

    // O += P V
    #pragma unroll
    for (int kk = 0; kk < 2; ++kk) {
      int dby = (kk * 32 + fg * 8) * 2;
      bf16x8 pf = *(const bf16x8*)(Pb + w * 2048 + fr * 128 + (dby ^ ((fr & 7) << 4)));
      #pragma unroll
      for (int dt = 0; dt < 4; ++dt) {
        int d = dt * 16 + fr;
        bf16x8 vf = *(const bf16x8*)(Vb + d * 128 + (dby ^ ((d & 7) << 4)));
        oacc[dt] = mfma16(pf, vf, oacc[dt]);
      }
    }
  }

  #pragma unroll
  for (int dt = 0; dt < 4; ++dt)
    #pragma unroll
    for (int j = 0; j < 4; ++j) {
      int t_loc = qt * 64 + w * 16 + fg * 4 + j;
      int dcol = h * 64 + dt * 16 + fr;
      og[((size_t)b * 2048 + t_loc) * 1024 + dcol] = f2bf(oacc[dt][j] / lrun[j]);
    }
}

// ---------------------------------------------------------------------------
extern "C" void kernel_launch(void* const* d_in, const int* in_sizes, int n_in,
                              void* d_out, int out_size, void* d_ws, size_t ws_size,
                              hipStream_t stream)
{
  (void)in_sizes; (void)n_in; (void)out_size; (void)ws_size;
  const float* x       = (const float*)d_in[0];
  const float* c       = (const float*)d_in[1];
  const int*   pos     = (const int*)d_in[2];
  const float* adaln_w = (const float*)d_in[3];
  const float* adaln_b = (const float*)d_in[4];
  const float* qkv_w   = (const float*)d_in[5];
  const float* lnq     = (const float*)d_in[6];
  const float* lnk     = (const float*)d_in[7];
  const float* proj_w  = (const float*)d_in[8];
  const float* proj_b  = (const float*)d_in[9];
  const float* w1_w    = (const float*)d_in[10];
  const float* w3_w    = (const float*)d_in[11];
  const float* w2_w    = (const float*)d_in[12];
  float* out = (float*)d_out;

  char* ws = (char*)d_ws;
  size_t off = 0;
  auto alloc = [&](size_t bytes) -> char* {
    char* p = ws + off; off += (bytes + 255) & ~(size_t)255; return p;
  };
  float* part    = (float*)alloc((size_t)8 * 2 * 6144 * 4);
  float* mods    = (float*)alloc((size_t)2 * 6144 * 4);
  float* ctab    = (float*)alloc((size_t)2048 * 32 * 4);
  float* stab    = (float*)alloc((size_t)2048 * 32 * 4);
  u16* qkv_wt    = (u16*)alloc((size_t)3072 * 1024 * 2);
  u16* proj_wt   = (u16*)alloc((size_t)1024 * 1024 * 2);
  u16* w1_wt     = (u16*)alloc((size_t)2816 * 1024 * 2);
  u16* w3_wt     = (u16*)alloc((size_t)2816 * 1024 * 2);
  u16* w2_wt     = (u16*)alloc((size_t)1024 * 2816 * 2);
  float* x1      = (float*)alloc((size_t)4096 * 1024 * 4);
  u16* attn_bf   = (u16*)alloc((size_t)4096 * 1024 * 2);
  char* pool = ws + off;   // phase-aliased region (~59 MB)
  // phase A
  u16* xmod_bf   = (u16*)(pool);
  u16* qkv_bf    = (u16*)(pool + 8388608);
  u16* q_bf      = (u16*)(pool + 33554432);
  u16* k_bf      = (u16*)(pool + 41943040);
  u16* v_bf      = (u16*)(pool + 50331648);
  // phase B (aliases phase A, which is dead by then)
  u16* h_bf      = (u16*)(pool);
  u16* t1_bf     = (u16*)(pool + 8388608);
  u16* hidden_bf = (u16*)(pool + 31457280);

  adaln1<<<dim3(24, 8), 256, 0, stream>>>(c, adaln_w, part);
  adaln2<<<48, 256, 0, stream>>>(part, adaln_b, mods);
  rope_table<<<256, 256, 0, stream>>>(pos, ctab, stab);
  rmsmod<<<4096, 256, 0, stream>>>(x, mods, xmod_bf, 0, 1024);
  transpose_w<<<dim3(96, 32), 256, 0, stream>>>(qkv_w, qkv_wt, 1024, 3072);
  transpose_w<<<dim3(32, 32), 256, 0, stream>>>(proj_w, proj_wt, 1024, 1024);
  transpose_w<<<dim3(88, 32), 256, 0, stream>>>(w1_w, w1_wt, 1024, 2816);
  transpose_w<<<dim3(88, 32), 256, 0, stream>>>(w3_w, w3_wt, 1024, 2816);
  transpose_w<<<dim3(32, 88), 256, 0, stream>>>(w2_w, w2_wt, 2816, 1024);

  gemm_bt<0><<<dim3(24, 32), 256, 0, stream>>>(xmod_bf, qkv_wt, 4096, 3072, 1024,
                                               nullptr, 0, nullptr, nullptr, nullptr,
                                               nullptr, qkv_bf);
  qknorm_rope<<<16384, 256, 0, stream>>>(qkv_bf, lnq, lnk, ctab, stab, q_bf, k_bf, v_bf);
  flash_attn<<<dim3(32, 16, 2), 256, 0, stream>>>(q_bf, k_bf, v_bf, attn_bf);
  gemm_bt<1><<<dim3(8, 32), 256, 0, stream>>>(attn_bf, proj_wt, 4096, 1024, 1024,
                                              mods, 2048, proj_b, x, nullptr,
                                              x1, nullptr);
  rmsmod<<<4096, 256, 0, stream>>>(x1, mods, h_bf, 3072, 4096);
  gemm_bt<2><<<dim3(22, 32), 256, 0, stream>>>(h_bf, w1_wt, 4096, 2816, 1024,
                                               nullptr, 0, nullptr, nullptr, nullptr,
                                               nullptr, t1_bf);
  gemm_bt<3><<<dim3(22, 32), 256, 0, stream>>>(h_bf, w3_wt, 4096, 2816, 1024,
                                               nullptr, 0, nullptr, nullptr, t1_bf,
                                               nullptr, hidden_bf);
  gemm_bt<4><<<dim3(8, 32), 256, 0, stream>>>(hidden_bf, w2_wt, 4096, 1024, 2816,
                                              mods, 5120, nullptr, x1, nullptr,
                                              out, nullptr);
}